// Round 1
// baseline (441.547 us; speedup 1.0000x reference)
//
#include <hip/hip_runtime.h>
#include <math.h>

#define KCOMP 8192
#define NSAMP 8192
#define BX 2048
#define DW 13

#define LOG2PI  1.8378770664093453f
#define LOGBETA 1.6094379124341003f   // ln(5)
#define LOGK    9.0109131020929380f   // ln(8192)

__device__ __forceinline__ float fast_exp(float x) {
    // e^x = 2^(x*log2(e)); v_exp_f32 handles overflow->inf, underflow->0
    return __builtin_amdgcn_exp2f(x * 1.44269504088896f);
}
__device__ __forceinline__ float fast_log(float x) {
    return __builtin_amdgcn_logf(x) * 0.69314718055995f;
}
__device__ __forceinline__ float fast_tanh(float z) {
    // tanh(z) = 1 - 2/(exp(2z)+1); exp2 form: exp(2z) = 2^(z*2*log2(e))
    float e = __builtin_amdgcn_exp2f(z * 2.88539008177793f);
    float r = __builtin_amdgcn_rcpf(e + 1.0f);   // e=inf -> r=0 -> tanh=1
    return fmaf(-2.0f, r, 1.0f);
}
__device__ __forceinline__ float softplus_stable(float x) {
    return fmaxf(x, 0.0f) + log1pf(expf(-fabsf(x)));
}

// ---------------------------------------------------------------- prep: per-component folds
__global__ void prep_kernel(const float* __restrict__ emp,
                            const float* __restrict__ rhos,
                            float* __restrict__ f1, float* __restrict__ f2) {
    int j = blockIdx.x * 256 + threadIdx.x;
    if (j >= KCOMP) return;
    float sp  = softplus_stable(rhos[j]);
    float var = sp * sp;
    float esq = 0.0f;
    #pragma unroll
    for (int c = 0; c < DW; ++c) {
        float e = emp[j * DW + c];
        esq = fmaf(e, e, esq);
    }
    float inv = 1.0f / var;
    f1[j] = -6.5f * (LOG2PI + logf(var)) - 0.5f * esq * inv;
    f2[j] = inv;
}

// ---------------------------------------------------------------- part A: data_lp (sum of diff^2)
// one wave per sample b; lanes stride over the 2048 x-points
__global__ __launch_bounds__(256) void data_kernel(
        const float* __restrict__ emp, const float* __restrict__ rhos,
        const float* __restrict__ x,   const float* __restrict__ y,
        const float* __restrict__ eps, const int* __restrict__ idxs,
        float* __restrict__ accum) {
    int tid  = threadIdx.x;
    int wave = tid >> 6;
    int lane = tid & 63;
    int b    = blockIdx.x * 4 + wave;

    int   i0 = idxs[b];
    float sp = softplus_stable(rhos[i0]);
    float w[DW];
    #pragma unroll
    for (int c = 0; c < DW; ++c)
        w[c] = fmaf(eps[b * DW + c], sp, emp[i0 * DW + c]);

    float acc = 0.0f;
    #pragma unroll 2
    for (int k = lane; k < BX; k += 64) {
        float t   = x[k];
        float h10 = fast_tanh(fmaf(w[0], t, w[2]));
        float h11 = fast_tanh(fmaf(w[1], t, w[3]));
        float h20 = fast_tanh(fmaf(w[4], h10, fmaf(w[5], h11, w[8])));
        float h21 = fast_tanh(fmaf(w[6], h10, fmaf(w[7], h11, w[9])));
        float yp  = fmaf(w[10], h20, fmaf(w[11], h21, w[12]));
        float d   = yp - y[k];
        acc = fmaf(d, d, acc);
    }
    #pragma unroll
    for (int o = 32; o; o >>= 1) acc += __shfl_down(acc, o);
    if (lane == 0) atomicAdd(accum, acc);
}

// ---------------------------------------------------------------- part B: KL (logsumexp over 8192 comps)
// block = 256 threads = 4 waves; each wave handles 4 rows; LDS-staged emp tile [c][64]
__global__ __launch_bounds__(256) void kl_kernel(
        const float* __restrict__ emp, const float* __restrict__ rhos,
        const float* __restrict__ eps, const int* __restrict__ idxs,
        const float* __restrict__ f1,  const float* __restrict__ f2,
        float* __restrict__ accum) {
    __shared__ float se[DW * 64];
    __shared__ float sf1[64];
    __shared__ float sf2[64];

    int tid  = threadIdx.x;
    int wave = tid >> 6;
    int lane = tid & 63;
    int rowbase = blockIdx.x * 16 + wave * 4;

    float w[4][DW];
    float halfwsq[4], P[4], s[4];
    #pragma unroll
    for (int r = 0; r < 4; ++r) {
        int   b  = rowbase + r;
        int   i0 = idxs[b];
        float sp = softplus_stable(rhos[i0]);
        float wsq = 0.0f, dot0 = 0.0f;
        #pragma unroll
        for (int c = 0; c < DW; ++c) {
            float e  = emp[i0 * DW + c];
            float wc = fmaf(eps[b * DW + c], sp, e);
            w[r][c] = wc;
            wsq  = fmaf(wc, wc, wsq);
            dot0 = fmaf(wc, e, dot0);
        }
        halfwsq[r] = 0.5f * wsq;
        // pivot = comp_lp at the sample's own component (near the max)
        P[r] = fmaf(f2[i0], dot0 - 0.5f * wsq, f1[i0]);
        s[r] = 0.0f;
    }

    for (int jc = 0; jc < KCOMP / 64; ++jc) {
        int base = jc * 64;
        __syncthreads();
        // coalesced global read of the 64x13 tile, transposed store into LDS [c][64]
        for (int wix = tid; wix < DW * 64; wix += 256) {
            int jl = wix / DW;
            int c  = wix - jl * DW;
            se[c * 64 + jl] = emp[base * DW + wix];
        }
        if (tid < 64)        sf1[tid]      = f1[base + tid];
        else if (tid < 128)  sf2[tid - 64] = f2[base + tid - 64];
        __syncthreads();

        float dot0 = 0.f, dot1 = 0.f, dot2 = 0.f, dot3 = 0.f;
        #pragma unroll
        for (int c = 0; c < DW; ++c) {
            float e = se[c * 64 + lane];
            dot0 = fmaf(e, w[0][c], dot0);
            dot1 = fmaf(e, w[1][c], dot1);
            dot2 = fmaf(e, w[2][c], dot2);
            dot3 = fmaf(e, w[3][c], dot3);
        }
        float a = sf1[lane], g = sf2[lane];
        s[0] += fast_exp(fmaf(g, dot0 - halfwsq[0], a) - P[0]);
        s[1] += fast_exp(fmaf(g, dot1 - halfwsq[1], a) - P[1]);
        s[2] += fast_exp(fmaf(g, dot2 - halfwsq[2], a) - P[2]);
        s[3] += fast_exp(fmaf(g, dot3 - halfwsq[3], a) - P[3]);
    }

    #pragma unroll
    for (int r = 0; r < 4; ++r) {
        float S = s[r];
        #pragma unroll
        for (int o = 32; o; o >>= 1) S += __shfl_down(S, o);
        if (lane == 0) {
            float q     = P[r] + fast_log(S) - LOGK;
            float prior = -halfwsq[r] - 6.5f * LOG2PI;
            atomicAdd(accum, q - prior);
        }
    }
}

// ---------------------------------------------------------------- finalize
__global__ void fin_kernel(const float* __restrict__ ws, float* __restrict__ out) {
    float S1 = ws[0];                    // sum of diff^2 over (b,k)
    float S2 = ws[1];                    // sum of (q_lp - prior_lp) over b
    float data_lp = -0.5f * 5.0f * S1 / (float)NSAMP
                    + (float)BX * 0.5f * (LOGBETA - LOG2PI);
    float kl = S2 / (float)NSAMP;
    out[0] = data_lp - kl;
}

extern "C" void kernel_launch(void* const* d_in, const int* in_sizes, int n_in,
                              void* d_out, int out_size, void* d_ws, size_t ws_size,
                              hipStream_t stream) {
    const float* emp  = (const float*)d_in[0];
    const float* rhos = (const float*)d_in[1];
    const float* x    = (const float*)d_in[2];
    const float* y    = (const float*)d_in[3];
    const float* eps  = (const float*)d_in[4];
    const int*   idxs = (const int*)d_in[5];
    float* out = (float*)d_out;

    float* ws = (float*)d_ws;
    float* f1 = ws + 16;
    float* f2 = ws + 16 + KCOMP;

    // zero the two accumulators (ws is poisoned 0xAA before every call)
    hipMemsetAsync(d_ws, 0, 2 * sizeof(float), stream);

    prep_kernel<<<KCOMP / 256, 256, 0, stream>>>(emp, rhos, f1, f2);
    data_kernel<<<NSAMP / 4, 256, 0, stream>>>(emp, rhos, x, y, eps, idxs, ws + 0);
    kl_kernel<<<NSAMP / 16, 256, 0, stream>>>(emp, rhos, eps, idxs, f1, f2, ws + 1);
    fin_kernel<<<1, 1, 0, stream>>>(ws, out);
}

// Round 2
// 148.446 us; speedup vs baseline: 2.9745x; 2.9745x over previous
//
#include <hip/hip_runtime.h>
#include <math.h>

#define KCOMP 8192
#define NSAMP 8192
#define BX 2048
#define DW 13

#define LOG2PI  1.8378770664093453f
#define LOGBETA 1.6094379124341003f   // ln(5)
#define LOGK    9.0109131020929380f   // ln(8192)
#define LOG2E   1.4426950408889634f

__device__ __forceinline__ float fast_log(float x) {
    return __builtin_amdgcn_logf(x) * 0.69314718055995f;
}
__device__ __forceinline__ float fast_tanh(float z) {
    float e = __builtin_amdgcn_exp2f(z * 2.88539008177793f);   // exp(2z)
    float r = __builtin_amdgcn_rcpf(e + 1.0f);                 // inf -> 0 -> tanh=1
    return fmaf(-2.0f, r, 1.0f);
}
__device__ __forceinline__ float softplus_stable(float x) {
    return fmaxf(x, 0.0f) + log1pf(expf(-fabsf(x)));
}
__device__ __forceinline__ unsigned short to_bf16(float f) {
    unsigned int u = __builtin_bit_cast(unsigned int, f);
    u += 0x7FFFu + ((u >> 16) & 1u);          // round-to-nearest-even
    return (unsigned short)(u >> 16);
}
__device__ __forceinline__ float from_bf16(unsigned short h) {
    unsigned int u = ((unsigned int)h) << 16;
    return __builtin_bit_cast(float, u);
}

// ws layout (floats)
#define OFF_PART   0        // [2048]  data per-block partials
#define OFF_RSUM   2048     // [8192]  per-row exp-sum (memset 0)
#define OFF_F1     10240    // [8192]
#define OFF_F2     18432    // [8192]
#define OFF_HQ     26624    // [8192]  0.5*||w||^2
#define OFF_P      34816    // [8192]  pivot (pre-scaled by LOG2E at use site)
#define OFF_WPAD   43008    // [8192*16]
#define OFF_EMPT   174080   // ushort[13*8192] viewed as bytes from here

// ------------------------------------------------ per-component folds + bf16 transpose
__global__ void prep_comp(const float* __restrict__ emp, const float* __restrict__ rhos,
                          float* __restrict__ f1, float* __restrict__ f2,
                          unsigned short* __restrict__ empT) {
    int j = blockIdx.x * 256 + threadIdx.x;
    float sp  = softplus_stable(rhos[j]);
    float var = sp * sp;
    float inv = 1.0f / var;
    float esq = 0.0f;
    #pragma unroll
    for (int c = 0; c < DW; ++c) {
        float e = emp[j * DW + c];
        esq = fmaf(e, e, esq);
        empT[c * KCOMP + j] = to_bf16(e);
    }
    f1[j] = -6.5f * (LOG2PI + logf(var)) - 0.5f * esq * inv;
    f2[j] = inv;
}

// ------------------------------------------------ per-row: w, 0.5||w||^2, pivot
__global__ void prep_row(const float* __restrict__ emp, const float* __restrict__ rhos,
                         const float* __restrict__ eps, const int* __restrict__ idxs,
                         const float* __restrict__ f1, const float* __restrict__ f2,
                         float* __restrict__ wpad, float* __restrict__ hq,
                         float* __restrict__ P) {
    int b  = blockIdx.x * 256 + threadIdx.x;
    int i0 = idxs[b];
    float sp  = softplus_stable(rhos[i0]);
    float wsq = 0.0f, dot = 0.0f;
    #pragma unroll
    for (int c = 0; c < DW; ++c) {
        float e  = emp[i0 * DW + c];
        float wc = fmaf(eps[b * DW + c], sp, e);
        wpad[b * 16 + c] = wc;
        wsq = fmaf(wc, wc, wsq);
        dot = fmaf(wc, e, dot);
    }
    wpad[b * 16 + 13] = 0.0f; wpad[b * 16 + 14] = 0.0f; wpad[b * 16 + 15] = 0.0f;
    float h = 0.5f * wsq;
    hq[b] = h;
    P[b]  = fmaf(f2[i0], dot - h, f1[i0]);   // comp_lp at own component: near the max
}

// ------------------------------------------------ part A: sum of (y_pred - y)^2
// one wave per row; per-block partial, NO global atomics
__global__ __launch_bounds__(256) void data_kernel(
        const float* __restrict__ wpad, const float* __restrict__ x,
        const float* __restrict__ y, float* __restrict__ part) {
    __shared__ float red[4];
    int tid = threadIdx.x, wave = tid >> 6, lane = tid & 63;
    int b = blockIdx.x * 4 + wave;

    float w[DW];
    #pragma unroll
    for (int c = 0; c < DW; ++c) w[c] = wpad[b * 16 + c];

    float acc = 0.0f;
    #pragma unroll 2
    for (int k = lane; k < BX; k += 64) {
        float t   = x[k];
        float h10 = fast_tanh(fmaf(w[0], t, w[2]));
        float h11 = fast_tanh(fmaf(w[1], t, w[3]));
        float h20 = fast_tanh(fmaf(w[4], h10, fmaf(w[5], h11, w[8])));
        float h21 = fast_tanh(fmaf(w[6], h10, fmaf(w[7], h11, w[9])));
        float yp  = fmaf(w[10], h20, fmaf(w[11], h21, w[12]));
        float d   = yp - y[k];
        acc = fmaf(d, d, acc);
    }
    #pragma unroll
    for (int o = 32; o; o >>= 1) acc += __shfl_down(acc, o);
    if (lane == 0) red[wave] = acc;
    __syncthreads();
    if (tid == 0) part[blockIdx.x] = red[0] + red[1] + red[2] + red[3];
}

// ------------------------------------------------ part B: partial exp-sums of LSE
// grid = (512 row-tiles, 4 comp-tiles); 4 waves/block, 4 rows/wave in registers;
// lanes = components, coalesced bf16 empT loads; no LDS, no syncthreads.
__global__ __launch_bounds__(256) void kl_kernel(
        const unsigned short* __restrict__ empT,
        const float* __restrict__ f1, const float* __restrict__ f2,
        const float* __restrict__ wpad, const float* __restrict__ hq,
        const float* __restrict__ Pp, float* __restrict__ rowsum) {
    int tid = threadIdx.x, wave = tid >> 6, lane = tid & 63;
    int rowbase = blockIdx.x * 16 + wave * 4;

    float w[4][DW], h[4], pl[4], s[4];
    #pragma unroll
    for (int r = 0; r < 4; ++r) {
        int b = rowbase + r;
        #pragma unroll
        for (int c = 0; c < DW; ++c) w[r][c] = wpad[b * 16 + c];
        h[r]  = hq[b];
        pl[r] = Pp[b] * LOG2E;
        s[r]  = 0.0f;
    }

    int cbase = blockIdx.y * (KCOMP / 4);
    for (int it = 0; it < (KCOMP / 4) / 64; ++it) {
        int j = cbase + it * 64 + lane;
        float e[DW];
        #pragma unroll
        for (int c = 0; c < DW; ++c) e[c] = from_bf16(empT[c * KCOMP + j]);
        float g2 = f2[j] * LOG2E;
        float a2 = f1[j] * LOG2E;
        #pragma unroll
        for (int r = 0; r < 4; ++r) {
            float dot = 0.0f;
            #pragma unroll
            for (int c = 0; c < DW; ++c) dot = fmaf(e[c], w[r][c], dot);
            float arg = fmaf(g2, dot - h[r], a2 - pl[r]);   // (clp - P) * log2(e)
            s[r] += __builtin_amdgcn_exp2f(arg);
        }
    }

    #pragma unroll
    for (int r = 0; r < 4; ++r) {
        float S = s[r];
        #pragma unroll
        for (int o = 32; o; o >>= 1) S += __shfl_down(S, o);
        if (lane == 0) atomicAdd(&rowsum[rowbase + r], S);   // 8192 addresses, 16 adds each
    }
}

// ------------------------------------------------ finalize: reduce partials + rows
__global__ __launch_bounds__(256) void fin_kernel(
        const float* __restrict__ part, const float* __restrict__ rowsum,
        const float* __restrict__ hq, const float* __restrict__ Pp,
        float* __restrict__ out) {
    __shared__ float red1[4], red2[4];
    int tid = threadIdx.x, wave = tid >> 6, lane = tid & 63;

    float s1 = 0.0f;
    for (int i = tid; i < 2048; i += 256) s1 += part[i];
    float s2 = 0.0f;
    for (int b = tid; b < NSAMP; b += 256) {
        float q     = Pp[b] + fast_log(rowsum[b]) - LOGK;
        float prior = -hq[b] - 6.5f * LOG2PI;
        s2 += q - prior;
    }
    #pragma unroll
    for (int o = 32; o; o >>= 1) { s1 += __shfl_down(s1, o); s2 += __shfl_down(s2, o); }
    if (lane == 0) { red1[wave] = s1; red2[wave] = s2; }
    __syncthreads();
    if (tid == 0) {
        float S1 = red1[0] + red1[1] + red1[2] + red1[3];
        float S2 = red2[0] + red2[1] + red2[2] + red2[3];
        float data_lp = -0.5f * 5.0f * S1 / (float)NSAMP
                        + (float)BX * 0.5f * (LOGBETA - LOG2PI);
        out[0] = data_lp - S2 / (float)NSAMP;
    }
}

extern "C" void kernel_launch(void* const* d_in, const int* in_sizes, int n_in,
                              void* d_out, int out_size, void* d_ws, size_t ws_size,
                              hipStream_t stream) {
    const float* emp  = (const float*)d_in[0];
    const float* rhos = (const float*)d_in[1];
    const float* x    = (const float*)d_in[2];
    const float* y    = (const float*)d_in[3];
    const float* eps  = (const float*)d_in[4];
    const int*   idxs = (const int*)d_in[5];
    float* out = (float*)d_out;

    float* ws = (float*)d_ws;
    float* part = ws + OFF_PART;
    float* rsum = ws + OFF_RSUM;
    float* f1   = ws + OFF_F1;
    float* f2   = ws + OFF_F2;
    float* hq   = ws + OFF_HQ;
    float* P    = ws + OFF_P;
    float* wpad = ws + OFF_WPAD;
    unsigned short* empT = (unsigned short*)(ws + OFF_EMPT);

    hipMemsetAsync(rsum, 0, NSAMP * sizeof(float), stream);

    prep_comp<<<KCOMP / 256, 256, 0, stream>>>(emp, rhos, f1, f2, empT);
    prep_row<<<NSAMP / 256, 256, 0, stream>>>(emp, rhos, eps, idxs, f1, f2, wpad, hq, P);
    data_kernel<<<NSAMP / 4, 256, 0, stream>>>(wpad, x, y, part);
    dim3 klgrid(NSAMP / 16, 4);
    kl_kernel<<<klgrid, 256, 0, stream>>>(empT, f1, f2, wpad, hq, P, rsum);
    fin_kernel<<<1, 256, 0, stream>>>(part, rsum, hq, P, out);
}

// Round 3
// 130.389 us; speedup vs baseline: 3.3864x; 1.1385x over previous
//
#include <hip/hip_runtime.h>
#include <math.h>

#define KCOMP 8192
#define NSAMP 8192
#define BX 2048
#define DW 13

#define LOG2PI  1.8378770664093453f
#define LOGBETA 1.6094379124341003f   // ln(5)
#define LOGK    9.0109131020929380f   // ln(8192)
#define LOG2E   1.4426950408889634f
#define LN2     0.6931471805599453f

typedef __attribute__((ext_vector_type(8))) short bf16x8_t;
typedef __attribute__((ext_vector_type(4))) float f32x4_t;

__device__ __forceinline__ float fast_log(float x) {
    return __builtin_amdgcn_logf(x) * LN2;
}
__device__ __forceinline__ float fast_tanh(float z) {
    float e = __builtin_amdgcn_exp2f(z * 2.88539008177793f);   // exp(2z)
    float r = __builtin_amdgcn_rcpf(e + 1.0f);                 // inf -> 0 -> tanh=1
    return fmaf(-2.0f, r, 1.0f);
}
__device__ __forceinline__ float softplus_stable(float x) {
    return fmaxf(x, 0.0f) + log1pf(expf(-fabsf(x)));
}
__device__ __forceinline__ unsigned short to_bf16(float f) {
    unsigned int u = __builtin_bit_cast(unsigned int, f);
    u += 0x7FFFu + ((u >> 16) & 1u);          // round-to-nearest-even
    return (unsigned short)(u >> 16);
}
__device__ __forceinline__ float from_bf16(unsigned short h) {
    unsigned int u = ((unsigned int)h) << 16;
    return __builtin_bit_cast(float, u);
}

// ---- ws layout (float offsets) ----
#define OFF_PART   0        // [2048]
#define OFF_RSUM   2048     // [8192]
#define OFF_F1     10240    // [8192]  unscaled
#define OFF_F2     18432    // [8192]  unscaled
#define OFF_G2     26624    // [8192]  f2*LOG2E
#define OFF_A2     34816    // [8192]  f1*LOG2E
#define OFF_HQ     43008    // [8192]  0.5*||w||^2
#define OFF_PL     51200    // [8192]  pivot*LOG2E
#define OFF_WB     59392    // ushort[8192*32]: [0..12]=hi(w),[16..28]=lo(w), pads 0
#define OFF_EMPB   190464   // ushort[8192*32]: [k]=bf16(e_k) k<13, dup at 16+k

// ------------------------------------------------ per-component folds + B-fragment build
__global__ void prep_comp(const float* __restrict__ emp, const float* __restrict__ rhos,
                          float* __restrict__ f1, float* __restrict__ f2,
                          float* __restrict__ G2, float* __restrict__ A2,
                          unsigned short* __restrict__ empB) {
    int j = blockIdx.x * 256 + threadIdx.x;
    float sp  = softplus_stable(rhos[j]);
    float var = sp * sp;
    float inv = 1.0f / var;
    float esq = 0.0f;
    #pragma unroll
    for (int c = 0; c < DW; ++c) {
        float e = emp[j * DW + c];
        esq = fmaf(e, e, esq);
        unsigned short eb = to_bf16(e);
        empB[j * 32 + c]      = eb;
        empB[j * 32 + 16 + c] = eb;
    }
    #pragma unroll
    for (int c = DW; c < 16; ++c) {
        empB[j * 32 + c] = 0;
        empB[j * 32 + 16 + c] = 0;
    }
    float f1v = -6.5f * (LOG2PI + logf(var)) - 0.5f * esq * inv;
    f1[j] = f1v;  f2[j] = inv;
    G2[j] = inv * LOG2E;
    A2[j] = f1v * LOG2E;
}

// ------------------------------------------------ per-row: hi/lo split of w, 0.5||w||^2, pivot
__global__ void prep_row(const float* __restrict__ emp, const float* __restrict__ rhos,
                         const float* __restrict__ eps, const int* __restrict__ idxs,
                         const float* __restrict__ f1, const float* __restrict__ f2,
                         unsigned short* __restrict__ wB, float* __restrict__ hq,
                         float* __restrict__ pl) {
    int b  = blockIdx.x * 256 + threadIdx.x;
    int i0 = idxs[b];
    float sp  = softplus_stable(rhos[i0]);
    float wsq = 0.0f, dot = 0.0f;
    #pragma unroll
    for (int c = 0; c < DW; ++c) {
        float e  = emp[i0 * DW + c];
        float wc = fmaf(eps[b * DW + c], sp, e);
        unsigned short hi = to_bf16(wc);
        unsigned short lo = to_bf16(wc - from_bf16(hi));
        wB[b * 32 + c]      = hi;
        wB[b * 32 + 16 + c] = lo;
        wsq = fmaf(wc, wc, wsq);
        dot = fmaf(wc, e, dot);
    }
    #pragma unroll
    for (int c = DW; c < 16; ++c) {
        wB[b * 32 + c] = 0;
        wB[b * 32 + 16 + c] = 0;
    }
    float h = 0.5f * wsq;
    hq[b] = h;
    float P = fmaf(f2[i0], dot - h, f1[i0]);     // comp_lp at own component (near max)
    pl[b] = P * LOG2E;
}

// ------------------------------------------------ part A: sum of (y_pred - y)^2
__global__ __launch_bounds__(256) void data_kernel(
        const unsigned short* __restrict__ wB, const float* __restrict__ x,
        const float* __restrict__ y, float* __restrict__ part) {
    __shared__ float red[4];
    int tid = threadIdx.x, wave = tid >> 6, lane = tid & 63;
    int b = blockIdx.x * 4 + wave;

    float w[DW];
    #pragma unroll
    for (int c = 0; c < DW; ++c)
        w[c] = from_bf16(wB[b * 32 + c]) + from_bf16(wB[b * 32 + 16 + c]);

    float acc = 0.0f;
    #pragma unroll 4
    for (int k = lane; k < BX; k += 64) {
        float t   = x[k];
        float h10 = fast_tanh(fmaf(w[0], t, w[2]));
        float h11 = fast_tanh(fmaf(w[1], t, w[3]));
        float h20 = fast_tanh(fmaf(w[4], h10, fmaf(w[5], h11, w[8])));
        float h21 = fast_tanh(fmaf(w[6], h10, fmaf(w[7], h11, w[9])));
        float yp  = fmaf(w[10], h20, fmaf(w[11], h21, w[12]));
        float d   = yp - y[k];
        acc = fmaf(d, d, acc);
    }
    #pragma unroll
    for (int o = 32; o; o >>= 1) acc += __shfl_down(acc, o);
    if (lane == 0) red[wave] = acc;
    __syncthreads();
    if (tid == 0) part[blockIdx.x] = red[0] + red[1] + red[2] + red[3];
}

// ------------------------------------------------ part B: MFMA GEMM + fused exp epilogue
// grid = (128 row-groups of 64, 8 comp-chunks of 1024); 4 waves/block, 16 rows/wave.
// One mfma_f32_16x16x32_bf16 per 16x16 C-tile: A = [w_hi | w_lo], B = [e | e].
__global__ __launch_bounds__(256) void kl_mfma(
        const unsigned short* __restrict__ empB,
        const float* __restrict__ G2, const float* __restrict__ A2,
        const float* __restrict__ hq, const float* __restrict__ pl,
        const unsigned short* __restrict__ wB, float* __restrict__ rowsum) {
    int tid = threadIdx.x, wave = tid >> 6, lane = tid & 63;
    int rowbase = blockIdx.x * 64 + wave * 16;
    int half = lane >> 4;      // 0..3 -> k-offset half*8; C rows half*4+reg
    int m16  = lane & 15;      // A row within group / C col (comp)

    const bf16x8_t afrag = *(const bf16x8_t*)(wB + (rowbase + m16) * 32 + half * 8);

    float h[4], p[4];
    #pragma unroll
    for (int r = 0; r < 4; ++r) {
        h[r] = hq[rowbase + half * 4 + r];
        p[r] = pl[rowbase + half * 4 + r];
    }
    float s[4] = {0.f, 0.f, 0.f, 0.f};

    int j0 = blockIdx.y * (KCOMP / 8);
    #pragma unroll 2
    for (int jt = 0; jt < (KCOMP / 8) / 16; ++jt) {
        int j = j0 + jt * 16 + m16;
        bf16x8_t bfrag = *(const bf16x8_t*)(empB + j * 32 + half * 8);
        f32x4_t c = {0.f, 0.f, 0.f, 0.f};
        c = __builtin_amdgcn_mfma_f32_16x16x32_bf16(afrag, bfrag, c, 0, 0, 0);
        float g2 = G2[j], a2 = A2[j];
        #pragma unroll
        for (int r = 0; r < 4; ++r) {
            float t = fmaf(-g2, h[r], a2 - p[r]);           // (a2 - g2*h_r - pl_r)
            s[r] += __builtin_amdgcn_exp2f(fmaf(g2, c[r], t));
        }
    }

    #pragma unroll
    for (int r = 0; r < 4; ++r) {
        float S = s[r];
        S += __shfl_xor(S, 1); S += __shfl_xor(S, 2);
        S += __shfl_xor(S, 4); S += __shfl_xor(S, 8);
        if (m16 == 0) atomicAdd(&rowsum[rowbase + half * 4 + r], S);
    }
}

// ------------------------------------------------ finalize
__global__ __launch_bounds__(256) void fin_kernel(
        const float* __restrict__ part, const float* __restrict__ rowsum,
        const float* __restrict__ hq, const float* __restrict__ pl,
        float* __restrict__ out) {
    __shared__ float red1[4], red2[4];
    int tid = threadIdx.x, wave = tid >> 6, lane = tid & 63;

    float s1 = 0.0f;
    for (int i = tid; i < 2048; i += 256) s1 += part[i];
    float s2 = 0.0f;
    for (int b = tid; b < NSAMP; b += 256) {
        float P     = pl[b] * LN2;
        float q     = P + fast_log(rowsum[b]) - LOGK;
        float prior = -hq[b] - 6.5f * LOG2PI;
        s2 += q - prior;
    }
    #pragma unroll
    for (int o = 32; o; o >>= 1) { s1 += __shfl_down(s1, o); s2 += __shfl_down(s2, o); }
    if (lane == 0) { red1[wave] = s1; red2[wave] = s2; }
    __syncthreads();
    if (tid == 0) {
        float S1 = red1[0] + red1[1] + red1[2] + red1[3];
        float S2 = red2[0] + red2[1] + red2[2] + red2[3];
        float data_lp = -0.5f * 5.0f * S1 / (float)NSAMP
                        + (float)BX * 0.5f * (LOGBETA - LOG2PI);
        out[0] = data_lp - S2 / (float)NSAMP;
    }
}

extern "C" void kernel_launch(void* const* d_in, const int* in_sizes, int n_in,
                              void* d_out, int out_size, void* d_ws, size_t ws_size,
                              hipStream_t stream) {
    const float* emp  = (const float*)d_in[0];
    const float* rhos = (const float*)d_in[1];
    const float* x    = (const float*)d_in[2];
    const float* y    = (const float*)d_in[3];
    const float* eps  = (const float*)d_in[4];
    const int*   idxs = (const int*)d_in[5];
    float* out = (float*)d_out;

    float* ws   = (float*)d_ws;
    float* part = ws + OFF_PART;
    float* rsum = ws + OFF_RSUM;
    float* f1   = ws + OFF_F1;
    float* f2   = ws + OFF_F2;
    float* G2   = ws + OFF_G2;
    float* A2   = ws + OFF_A2;
    float* hq   = ws + OFF_HQ;
    float* pl   = ws + OFF_PL;
    unsigned short* wB   = (unsigned short*)(ws + OFF_WB);
    unsigned short* empB = (unsigned short*)(ws + OFF_EMPB);

    hipMemsetAsync(rsum, 0, NSAMP * sizeof(float), stream);

    prep_comp<<<KCOMP / 256, 256, 0, stream>>>(emp, rhos, f1, f2, G2, A2, empB);
    prep_row<<<NSAMP / 256, 256, 0, stream>>>(emp, rhos, eps, idxs, f1, f2, wB, hq, pl);
    data_kernel<<<NSAMP / 4, 256, 0, stream>>>(wB, x, y, part);
    dim3 klgrid(NSAMP / 64, 8);
    kl_mfma<<<klgrid, 256, 0, stream>>>(empB, G2, A2, hq, pl, wB, rsum);
    fin_kernel<<<1, 256, 0, stream>>>(part, rsum, hq, pl, out);
}

// Round 4
// 124.195 us; speedup vs baseline: 3.5553x; 1.0499x over previous
//
#include <hip/hip_runtime.h>
#include <math.h>

#define KCOMP 8192
#define NSAMP 8192
#define BX 2048
#define DW 13

#define LOG2PI  1.8378770664093453f
#define LOGBETA 1.6094379124341003f   // ln(5)
#define LOGK    9.0109131020929380f   // ln(8192)
#define LOG2E   1.4426950408889634f
#define LN2     0.6931471805599453f

#define NBLK_DATA 2048
#define NBLK_KL   1024      // 128 row-tiles x 8 comp-chunks

typedef __attribute__((ext_vector_type(8))) short bf16x8_t;
typedef __attribute__((ext_vector_type(4))) float f32x4_t;

__device__ __forceinline__ float fast_log(float x) {
    return __builtin_amdgcn_logf(x) * LN2;
}
__device__ __forceinline__ float fast_tanh(float z) {
    float e = __builtin_amdgcn_exp2f(z * 2.88539008177793f);   // exp(2z)
    float r = __builtin_amdgcn_rcpf(e + 1.0f);                 // inf -> 0 -> tanh=1
    return fmaf(-2.0f, r, 1.0f);
}
__device__ __forceinline__ float softplus_stable(float x) {
    return fmaxf(x, 0.0f) + log1pf(expf(-fabsf(x)));
}
__device__ __forceinline__ unsigned short to_bf16(float f) {
    unsigned int u = __builtin_bit_cast(unsigned int, f);
    u += 0x7FFFu + ((u >> 16) & 1u);          // round-to-nearest-even
    return (unsigned short)(u >> 16);
}
__device__ __forceinline__ float from_bf16(unsigned short h) {
    unsigned int u = ((unsigned int)h) << 16;
    return __builtin_bit_cast(float, u);
}

// ---- ws layout (float offsets) ----
#define OFF_PART   0        // [2048]
#define OFF_RSUM   2048     // [8192]  zeroed by prep
#define OFF_G2     10240    // [8192]  f2*LOG2E
#define OFF_A2     18432    // [8192]  f1*LOG2E
#define OFF_HQ     26624    // [8192]  0.5*||w||^2
#define OFF_PL     34816    // [8192]  pivot*LOG2E
#define OFF_WB     43008    // ushort[8192*32]: [0..12]=hi(w), [16..28]=lo(w), pads 0
#define OFF_EMPB   174080   // ushort[8192*32]: bf16(e) duplicated in both halves

// ================================================ prep: comp folds + row folds + rsum zero
// thread t handles component j=t AND row b=t (independent jobs, same width)
__global__ __launch_bounds__(256) void prep_kernel(
        const float* __restrict__ emp, const float* __restrict__ rhos,
        const float* __restrict__ eps, const int* __restrict__ idxs,
        unsigned short* __restrict__ empB, float* __restrict__ G2,
        float* __restrict__ A2, unsigned short* __restrict__ wB,
        float* __restrict__ hq, float* __restrict__ pl, float* __restrict__ rsum) {
    int t = blockIdx.x * 256 + threadIdx.x;

    // ---- component part (j = t) ----
    {
        float sp  = softplus_stable(rhos[t]);
        float var = sp * sp;
        float inv = 1.0f / var;
        float esq = 0.0f;
        #pragma unroll
        for (int c = 0; c < DW; ++c) {
            float e = emp[t * DW + c];
            esq = fmaf(e, e, esq);
            unsigned short eb = to_bf16(e);
            empB[t * 32 + c]      = eb;
            empB[t * 32 + 16 + c] = eb;
        }
        #pragma unroll
        for (int c = DW; c < 16; ++c) {
            empB[t * 32 + c] = 0;
            empB[t * 32 + 16 + c] = 0;
        }
        float f1v = -6.5f * (LOG2PI + logf(var)) - 0.5f * esq * inv;
        G2[t] = inv * LOG2E;
        A2[t] = f1v * LOG2E;
        rsum[t] = 0.0f;
    }

    // ---- row part (b = t), f1/f2 recomputed inline for i0 ----
    {
        int   i0  = idxs[t];
        float sp  = softplus_stable(rhos[i0]);
        float var = sp * sp;
        float inv = 1.0f / var;
        float esq = 0.0f, wsq = 0.0f, dot = 0.0f;
        #pragma unroll
        for (int c = 0; c < DW; ++c) {
            float e  = emp[i0 * DW + c];
            float wc = fmaf(eps[t * DW + c], sp, e);
            esq = fmaf(e, e, esq);
            wsq = fmaf(wc, wc, wsq);
            dot = fmaf(wc, e, dot);
            unsigned short hi = to_bf16(wc);
            unsigned short lo = to_bf16(wc - from_bf16(hi));
            wB[t * 32 + c]      = hi;
            wB[t * 32 + 16 + c] = lo;
        }
        #pragma unroll
        for (int c = DW; c < 16; ++c) {
            wB[t * 32 + c] = 0;
            wB[t * 32 + 16 + c] = 0;
        }
        float f1v = -6.5f * (LOG2PI + logf(var)) - 0.5f * esq * inv;
        float h   = 0.5f * wsq;
        hq[t] = h;
        pl[t] = fmaf(inv, dot - h, f1v) * LOG2E;   // pivot * log2(e)
    }
}

// ================================================ fused main: data (blocks 0..2047) + kl (2048..3071)
__global__ __launch_bounds__(256) void main_kernel(
        const unsigned short* __restrict__ empB, const float* __restrict__ G2,
        const float* __restrict__ A2, const float* __restrict__ hq,
        const float* __restrict__ pl, const unsigned short* __restrict__ wB,
        const float* __restrict__ x, const float* __restrict__ y,
        float* __restrict__ part, float* __restrict__ rowsum) {
    int tid = threadIdx.x, wave = tid >> 6, lane = tid & 63;

    if (blockIdx.x < NBLK_DATA) {
        // ---------------- data part: one wave per row, 4-point ILP per lane ----------------
        __shared__ float red[4];
        int b = blockIdx.x * 4 + wave;

        float w[DW];
        #pragma unroll
        for (int c = 0; c < DW; ++c)
            w[c] = from_bf16(wB[b * 32 + c]) + from_bf16(wB[b * 32 + 16 + c]);

        const float4* x4 = (const float4*)x;
        const float4* y4 = (const float4*)y;

        float acc = 0.0f;
        #pragma unroll 2
        for (int it = 0; it < BX / 4 / 64; ++it) {
            int k = it * 64 + lane;
            float4 tv = x4[k];
            float4 yv = y4[k];
            float tt[4] = {tv.x, tv.y, tv.z, tv.w};
            float yy[4] = {yv.x, yv.y, yv.z, yv.w};
            float h10[4], h11[4], h20[4], h21[4];
            #pragma unroll
            for (int p = 0; p < 4; ++p) h10[p] = fast_tanh(fmaf(w[0], tt[p], w[2]));
            #pragma unroll
            for (int p = 0; p < 4; ++p) h11[p] = fast_tanh(fmaf(w[1], tt[p], w[3]));
            #pragma unroll
            for (int p = 0; p < 4; ++p)
                h20[p] = fast_tanh(fmaf(w[4], h10[p], fmaf(w[5], h11[p], w[8])));
            #pragma unroll
            for (int p = 0; p < 4; ++p)
                h21[p] = fast_tanh(fmaf(w[6], h10[p], fmaf(w[7], h11[p], w[9])));
            #pragma unroll
            for (int p = 0; p < 4; ++p) {
                float yp = fmaf(w[10], h20[p], fmaf(w[11], h21[p], w[12]));
                float d  = yp - yy[p];
                acc = fmaf(d, d, acc);
            }
        }
        #pragma unroll
        for (int o = 32; o; o >>= 1) acc += __shfl_down(acc, o);
        if (lane == 0) red[wave] = acc;
        __syncthreads();
        if (tid == 0) part[blockIdx.x] = red[0] + red[1] + red[2] + red[3];
    } else {
        // ---------------- kl part: MFMA GEMM + fused exp epilogue ----------------
        int bid     = blockIdx.x - NBLK_DATA;          // 0..1023
        int rowtile = bid & 127;
        int chunk   = bid >> 7;                        // 0..7
        int rowbase = rowtile * 64 + wave * 16;
        int half = lane >> 4;          // k-offset half*8; C rows half*4+r
        int m16  = lane & 15;          // A row in tile / comp col

        const bf16x8_t afrag = *(const bf16x8_t*)(wB + (rowbase + m16) * 32 + half * 8);

        float h[4], p[4];
        #pragma unroll
        for (int r = 0; r < 4; ++r) {
            h[r] = hq[rowbase + half * 4 + r];
            p[r] = pl[rowbase + half * 4 + r];
        }
        float s[4] = {0.f, 0.f, 0.f, 0.f};

        int j0 = chunk * (KCOMP / 8);
        #pragma unroll 2
        for (int jt = 0; jt < (KCOMP / 8) / 16; ++jt) {
            int j = j0 + jt * 16 + m16;
            bf16x8_t bfrag = *(const bf16x8_t*)(empB + j * 32 + half * 8);
            f32x4_t c = {0.f, 0.f, 0.f, 0.f};
            c = __builtin_amdgcn_mfma_f32_16x16x32_bf16(afrag, bfrag, c, 0, 0, 0);
            float g2 = G2[j], a2 = A2[j];
            #pragma unroll
            for (int r = 0; r < 4; ++r) {
                float t = fmaf(-g2, h[r], a2 - p[r]);
                s[r] += __builtin_amdgcn_exp2f(fmaf(g2, c[r], t));
            }
        }

        #pragma unroll
        for (int r = 0; r < 4; ++r) {
            float S = s[r];
            S += __shfl_xor(S, 1); S += __shfl_xor(S, 2);
            S += __shfl_xor(S, 4); S += __shfl_xor(S, 8);
            if (m16 == 0) atomicAdd(&rowsum[rowbase + half * 4 + r], S);
        }
    }
}

// ================================================ finalize
__global__ __launch_bounds__(256) void fin_kernel(
        const float* __restrict__ part, const float* __restrict__ rowsum,
        const float* __restrict__ hq, const float* __restrict__ pl,
        float* __restrict__ out) {
    __shared__ float red1[4], red2[4];
    int tid = threadIdx.x, wave = tid >> 6, lane = tid & 63;

    float s1 = 0.0f;
    for (int i = tid; i < NBLK_DATA; i += 256) s1 += part[i];
    float s2 = 0.0f;
    for (int b = tid; b < NSAMP; b += 256) {
        float P     = pl[b] * LN2;
        float q     = P + fast_log(rowsum[b]) - LOGK;
        float prior = -hq[b] - 6.5f * LOG2PI;
        s2 += q - prior;
    }
    #pragma unroll
    for (int o = 32; o; o >>= 1) { s1 += __shfl_down(s1, o); s2 += __shfl_down(s2, o); }
    if (lane == 0) { red1[wave] = s1; red2[wave] = s2; }
    __syncthreads();
    if (tid == 0) {
        float S1 = red1[0] + red1[1] + red1[2] + red1[3];
        float S2 = red2[0] + red2[1] + red2[2] + red2[3];
        float data_lp = -0.5f * 5.0f * S1 / (float)NSAMP
                        + (float)BX * 0.5f * (LOGBETA - LOG2PI);
        out[0] = data_lp - S2 / (float)NSAMP;
    }
}

extern "C" void kernel_launch(void* const* d_in, const int* in_sizes, int n_in,
                              void* d_out, int out_size, void* d_ws, size_t ws_size,
                              hipStream_t stream) {
    const float* emp  = (const float*)d_in[0];
    const float* rhos = (const float*)d_in[1];
    const float* x    = (const float*)d_in[2];
    const float* y    = (const float*)d_in[3];
    const float* eps  = (const float*)d_in[4];
    const int*   idxs = (const int*)d_in[5];
    float* out = (float*)d_out;

    float* ws   = (float*)d_ws;
    float* part = ws + OFF_PART;
    float* rsum = ws + OFF_RSUM;
    float* G2   = ws + OFF_G2;
    float* A2   = ws + OFF_A2;
    float* hq   = ws + OFF_HQ;
    float* pl   = ws + OFF_PL;
    unsigned short* wB   = (unsigned short*)(ws + OFF_WB);
    unsigned short* empB = (unsigned short*)(ws + OFF_EMPB);

    prep_kernel<<<KCOMP / 256, 256, 0, stream>>>(emp, rhos, eps, idxs,
                                                 empB, G2, A2, wB, hq, pl, rsum);
    main_kernel<<<NBLK_DATA + NBLK_KL, 256, 0, stream>>>(empB, G2, A2, hq, pl, wB,
                                                         x, y, part, rsum);
    fin_kernel<<<1, 256, 0, stream>>>(part, rsum, hq, pl, out);
}